// Round 2
// baseline (438.701 us; speedup 1.0000x reference)
//
#include <hip/hip_runtime.h>
#include <cstdint>
#include <cstddef>

// SummaryAdapter fused kernel for MI355X (gfx950), v2: 16-row S-tiles,
// 2 blocks/CU for memory/compute overlap across blocks.
// L=8 B=2 S=4096 D=2048 N=128 Ds=1024 Da=64.
//
// Workspace layout (bytes):          off      size
//   KF  frag bf16                      0    262144
//   VF  frag bf16                 262144    262144
//   WqF frag bf16                 524288   2097152
//   WoF frag bf16                2621440   2097152
// Requires ws_size >= 4718592.

typedef __attribute__((ext_vector_type(8))) short short8;   // 8 x bf16 (4 VGPR)
typedef __attribute__((ext_vector_type(4))) float f32x4;
typedef __attribute__((ext_vector_type(4))) unsigned short u16x4;

#define MFMA16(a, b, c) __builtin_amdgcn_mfma_f32_16x16x32_bf16((a), (b), (c), 0, 0, 0)

__device__ __forceinline__ unsigned short f2bf(float f) {
  unsigned int x = __builtin_bit_cast(unsigned int, f);
  x += 0x7fffu + ((x >> 16) & 1u);        // RNE
  return (unsigned short)(x >> 16);
}
__device__ __forceinline__ float bf2f(unsigned short u) {
  return __builtin_bit_cast(float, (unsigned int)u << 16);
}
__device__ __forceinline__ short8 cvt8v(f32x4 a, f32x4 b) {
  short8 r;
  r[0] = (short)f2bf(a[0]); r[1] = (short)f2bf(a[1]);
  r[2] = (short)f2bf(a[2]); r[3] = (short)f2bf(a[3]);
  r[4] = (short)f2bf(b[0]); r[5] = (short)f2bf(b[1]);
  r[6] = (short)f2bf(b[2]); r[7] = (short)f2bf(b[3]);
  return r;
}
__device__ __forceinline__ short8 ld_cvt8(const float* p) {
  f32x4 v0 = *(const f32x4*)p, v1 = *(const f32x4*)(p + 4);
  return cvt8v(v0, v1);
}

// ---------------- pre 1: K = bank@Wk^T, V = bank@Wv^T via MFMA -------------
// grid 32: bid = ((l*2+b)*2 + kv). Reads f32 directly, converts inline.
// Writes KF/VF in B-fragment lane order.
__global__ __launch_bounds__(256)
void pre_kv_kernel(const float* __restrict__ bank,
                   const float* __restrict__ Wk,
                   const float* __restrict__ Wv,
                   unsigned short* __restrict__ KF, unsigned short* __restrict__ VF) {
  int bid = blockIdx.x;
  int l = bid >> 2, b = (bid >> 1) & 1, kv = bid & 1;
  int tid = threadIdx.x, wave = tid >> 6, lane = tid & 63;
  int lo = lane & 15, hi = lane >> 4;
  const float* W  = (kv ? Wv : Wk) + (size_t)l * 65536;
  const float* bk = bank + (size_t)b * 131072;
  int lbq = l * 2 + b;
  for (int it = 0; it < 2; ++it) {
    int nt = wave * 2 + it;                          // n-tile 0..7
    f32x4 acc[4];
    for (int at = 0; at < 4; ++at) acc[at] = (f32x4){0.f, 0.f, 0.f, 0.f};
    for (int ks = 0; ks < 32; ++ks) {
      short8 A = ld_cvt8(bk + (nt * 16 + lo) * 1024 + ks * 32 + hi * 8);
      #pragma unroll
      for (int at = 0; at < 4; ++at) {
        short8 B = ld_cvt8(W + (at * 16 + lo) * 1024 + ks * 32 + hi * 8);
        acc[at] = MFMA16(A, B, acc[at]);
      }
    }
    for (int at = 0; at < 4; ++at)
      for (int r = 0; r < 4; ++r) {
        int n = nt * 16 + hi * 4 + r;
        int a = at * 16 + lo;
        unsigned short v = f2bf(acc[at][r]);
        if (kv == 0) {  // KF: n=nt*16+(ln&15), a=ks*32+(ln>>4)*8+j
          int idx = ((lbq * 8 + (n >> 4)) * 2 + (a >> 5)) * 512 +
                    (((a >> 3) & 3) * 16 + (n & 15)) * 8 + (a & 7);
          KF[idx] = v;
        } else {        // VF: a=at*16+(ln&15), n=ks*32+(ln>>4)*8+j
          int idx = ((lbq * 4 + (a >> 4)) * 4 + (n >> 5)) * 512 +
                    (((n >> 3) & 3) * 16 + (a & 15)) * 8 + (n & 7);
          VF[idx] = v;
        }
      }
  }
}

// ---------------- pre 2: Wq/Wo -> bf16 fragment layout ---------------------
__global__ void pre_frag_kernel(const float* __restrict__ Wq, const float* __restrict__ Wo,
                                unsigned short* __restrict__ WqF, unsigned short* __restrict__ WoF) {
  int idx = blockIdx.x * 256 + threadIdx.x;        // 262144 threads
  if (idx < 131072) {
    int t = idx;
    int lane = t & 63, ks = (t >> 6) & 63, at = (t >> 12) & 3, l = t >> 14;
    int a = at * 16 + (lane & 15), d = ks * 32 + (lane >> 4) * 8;
    *(short8*)(WqF + (size_t)t * 8) = ld_cvt8(Wq + ((size_t)(l * 64 + a)) * 2048 + d);
  } else {
    int t = idx - 131072;
    int lane = t & 63, ks = (t >> 6) & 1, dt = (t >> 7) & 127, l = t >> 14;
    int d = dt * 16 + (lane & 15), a = ks * 32 + (lane >> 4) * 8;
    *(short8*)(WoF + (size_t)t * 8) = ld_cvt8(Wo + ((size_t)(l * 2048 + d)) * 64 + a);
  }
}

// ---------------- main fused kernel ----------------------------------------
// grid 4096 = (l:8, b:2, stile:256), 256 threads (4 waves), 78336 B dynamic LDS.
//   h_lds : bf16 [16][2048], swizzled byte ^= (row&7)<<4            65536 B
//   qs    : f32, Q [16][68] then scores [16][132] then attn_out      8448 B
//   P     : bf16 [16 rows][272 B/row]                                4352 B
// 2 blocks/CU (LDS-limited): independent barrier groups overlap HBM & MFMA.
#define QS_OFF 65536
#define P_OFF  (65536 + 8448)
__global__ __launch_bounds__(256, 2)
void adapter_main(const float* __restrict__ hidden,
                  const unsigned short* __restrict__ KF, const unsigned short* __restrict__ VF,
                  const unsigned short* __restrict__ WqF, const unsigned short* __restrict__ WoF,
                  const float* __restrict__ gates, float* __restrict__ out) {
  extern __shared__ char smem[];
  float* qs = (float*)(smem + QS_OFF);

  // XCD-bijective swizzle (4096 % 8 == 0): each XCD gets 512 consecutive
  // blocks => mostly one layer's weight fragments resident in its L2.
  int bid0 = blockIdx.x;
  int bid = (bid0 & 7) * 512 + (bid0 >> 3);
  int st = bid & 255, b = (bid >> 8) & 1, l = bid >> 9;
  int s0 = st * 16;
  int tid = threadIdx.x, wave = tid >> 6, lane = tid & 63;
  int lo = lane & 15, hi = lane >> 4;
  size_t hbase = ((size_t)(l * 2 + b) * 4096 + s0) * 2048;
  const float* hsrc = hidden + hbase;
  float gate = 1.0f / (1.0f + __expf(-gates[l]));

  // ---- Phase 0: stage hidden tile -> LDS bf16 (swizzled) ----
  #pragma unroll
  for (int it = 0; it < 16; ++it) {
    int chunk = tid + it * 256;                 // 4096 chunks of 8 f32
    int row = chunk >> 8, c = chunk & 255;
    const float* src = hsrc + row * 2048 + c * 8;
    f32x4 v0 = *(const f32x4*)src, v1 = *(const f32x4*)(src + 4);
    int byte = row * 4096 + ((c * 16) ^ ((row & 7) << 4));
    *(short8*)(smem + byte) = cvt8v(v0, v1);
  }
  __syncthreads();

  int at = wave;                                 // 0..3 : Da 16-col tile

  // ---- Phase 1: Q = h @ Wq^T (per wave one 16x16 C-tile, K=2048) ----
  {
    f32x4 acc = {0.f, 0.f, 0.f, 0.f};
    int abase = lo * 4096, sw = (lo & 7) << 4;
    const unsigned short* wq = WqF + ((size_t)(l * 4 + at) * 64) * 512 + lane * 8;
    #pragma unroll 8
    for (int ks = 0; ks < 64; ++ks) {
      short8 A = *(const short8*)(smem + abase + ((ks * 64 + hi * 16) ^ sw));
      short8 B = *(const short8*)(wq + ks * 512);
      acc = MFMA16(A, B, acc);
    }
    #pragma unroll
    for (int r = 0; r < 4; ++r)                  // fold 1/sqrt(64) into Q
      qs[(hi * 4 + r) * 68 + at * 16 + lo] = acc[r] * 0.125f;
  }
  __syncthreads();

  // ---- Phase 2a: build Q A-fragments (scores region aliases Q region) ----
  short8 afrag[2];
  #pragma unroll
  for (int ks = 0; ks < 2; ++ks) {
    const float* qp = qs + lo * 68 + ks * 32 + hi * 8;
    afrag[ks] = cvt8v(*(const f32x4*)qp, *(const f32x4*)(qp + 4));
  }
  __syncthreads();

  // ---- Phase 2b: scores = Q @ K^T -> qs region (stride 132) ----
  #pragma unroll
  for (int i = 0; i < 2; ++i) {
    int nt = wave * 2 + i;                       // 0..7
    f32x4 acc = {0.f, 0.f, 0.f, 0.f};
    const unsigned short* kf = KF + ((size_t)((l * 2 + b) * 8 + nt) * 2) * 512 + lane * 8;
    acc = MFMA16(afrag[0], *(const short8*)(kf), acc);
    acc = MFMA16(afrag[1], *(const short8*)(kf + 512), acc);
    #pragma unroll
    for (int r = 0; r < 4; ++r)
      qs[(hi * 4 + r) * 132 + nt * 16 + lo] = acc[r];
  }
  __syncthreads();

  // ---- Phase 3: softmax over N=128 (16 lanes per row) -> P bf16 ----
  {
    int row = wave * 4 + hi;
    const float* sp = qs + row * 132 + lo * 8;
    f32x4 v0 = *(const f32x4*)sp, v1 = *(const f32x4*)(sp + 4);
    float m = fmaxf(fmaxf(fmaxf(v0[0], v0[1]), fmaxf(v0[2], v0[3])),
                    fmaxf(fmaxf(v1[0], v1[1]), fmaxf(v1[2], v1[3])));
    m = fmaxf(m, __shfl_xor(m, 1)); m = fmaxf(m, __shfl_xor(m, 2));
    m = fmaxf(m, __shfl_xor(m, 4)); m = fmaxf(m, __shfl_xor(m, 8));
    f32x4 e0, e1; float s = 0.f;
    #pragma unroll
    for (int j = 0; j < 4; ++j) { e0[j] = __expf(v0[j] - m); s += e0[j]; }
    #pragma unroll
    for (int j = 0; j < 4; ++j) { e1[j] = __expf(v1[j] - m); s += e1[j]; }
    s += __shfl_xor(s, 1); s += __shfl_xor(s, 2);
    s += __shfl_xor(s, 4); s += __shfl_xor(s, 8);
    float inv = 1.0f / s;
    #pragma unroll
    for (int j = 0; j < 4; ++j) { e0[j] *= inv; e1[j] *= inv; }
    *(short8*)(smem + P_OFF + row * 272 + lo * 16) = cvt8v(e0, e1);
  }
  __syncthreads();

  // ---- Phase 4: attn_out = P @ V ----
  f32x4 aoacc = {0.f, 0.f, 0.f, 0.f};
  {
    const unsigned short* vf = VF + ((size_t)((l * 2 + b) * 4 + at) * 4) * 512 + lane * 8;
    #pragma unroll
    for (int ks = 0; ks < 4; ++ks) {
      short8 A = *(const short8*)(smem + P_OFF + lo * 272 + ks * 64 + hi * 16);
      short8 B = *(const short8*)(vf + ks * 512);
      aoacc = MFMA16(A, B, aoacc);
    }
  }
  __syncthreads();                               // all P reads done
  #pragma unroll
  for (int r = 0; r < 4; ++r)                    // attn_out into qs region
    qs[(hi * 4 + r) * 68 + at * 16 + lo] = aoacc[r];
  __syncthreads();

  // ---- Phase 5: resid^T = Wo @ attn_out^T, epilogue out = h + g*resid ----
  {
    short8 bfrag[2];                             // attn_out^T B-fragments
    #pragma unroll
    for (int ks = 0; ks < 2; ++ks) {
      const float* ap = qs + lo * 68 + ks * 32 + hi * 8;
      bfrag[ks] = cvt8v(*(const f32x4*)ap, *(const f32x4*)(ap + 4));
    }
    #pragma unroll 4
    for (int i = 0; i < 32; ++i) {
      int dt = wave + i * 4;                     // 0..127 d-tile
      const unsigned short* wo = WoF + ((size_t)(l * 128 + dt) * 2) * 512 + lane * 8;
      short8 A0 = *(const short8*)(wo);
      short8 A1 = *(const short8*)(wo + 512);
      f32x4 acc = {0.f, 0.f, 0.f, 0.f};
      acc = MFMA16(A0, bfrag[0], acc);
      acc = MFMA16(A1, bfrag[1], acc);
      int srow = lo;                             // s within tile
      int d0 = dt * 16 + hi * 4;                 // 4 consecutive d
      u16x4 hv = *(const u16x4*)(smem + srow * 4096 + ((d0 * 2) ^ ((srow & 7) << 4)));
      f32x4 o;
      #pragma unroll
      for (int r = 0; r < 4; ++r) o[r] = bf2f(hv[r]) + gate * acc[r];
      *(f32x4*)(out + hbase + (size_t)srow * 2048 + d0) = o;
    }
  }
}

extern "C" void kernel_launch(void* const* d_in, const int* in_sizes, int n_in,
                              void* d_out, int out_size, void* d_ws, size_t ws_size,
                              hipStream_t stream) {
  const float* hidden = (const float*)d_in[0];
  const float* bank   = (const float*)d_in[1];
  const float* Wq     = (const float*)d_in[2];
  const float* Wk     = (const float*)d_in[3];
  const float* Wv     = (const float*)d_in[4];
  const float* Wo     = (const float*)d_in[5];
  const float* gates  = (const float*)d_in[6];
  float* out = (float*)d_out;

  char* ws = (char*)d_ws;
  unsigned short* KF  = (unsigned short*)(ws);
  unsigned short* VF  = (unsigned short*)(ws + 262144);
  unsigned short* WqF = (unsigned short*)(ws + 524288);
  unsigned short* WoF = (unsigned short*)(ws + 2621440);

  pre_kv_kernel<<<32, 256, 0, stream>>>(bank, Wk, Wv, KF, VF);
  pre_frag_kernel<<<1024, 256, 0, stream>>>(Wq, Wo, WqF, WoF);

  (void)hipFuncSetAttribute(reinterpret_cast<const void*>(adapter_main),
                            hipFuncAttributeMaxDynamicSharedMemorySize, 78336);
  adapter_main<<<4096, 256, 78336, stream>>>(hidden, KF, VF, WqF, WoF, gates, out);
}